// Round 17
// baseline (246.571 us; speedup 1.0000x reference)
//
#include <hip/hip_runtime.h>
#include <math.h>

#define LSEQ 512
#define CDIM 192
#define DIN  384
#define NST  48
#define RNK  12
#define NB   8
#define NCH  16   // scan chunks (32 long)
#define LCH  32   // chunk length

static __device__ __forceinline__ float sigmoidf_(float x) { return 1.f / (1.f + __expf(-x)); }

typedef __attribute__((ext_vector_type(8))) short bshort8;
typedef __attribute__((ext_vector_type(4))) float f32x4;

static __device__ __forceinline__ short f2bf(float x) {
    unsigned u = __float_as_uint(x);
    unsigned r = (u + 0x7FFFu + ((u >> 16) & 1u)) >> 16;   // RNE
    return (short)r;
}
static __device__ __forceinline__ float bfhi2f(unsigned pk) { return __uint_as_float(pk & 0xffff0000u); }
static __device__ __forceinline__ float bflo2f(unsigned pk) { return __uint_as_float(pk << 16); }

// ---------------- bf16 MFMA GEMM (tile-templated) ----------------
// MODE 0: plain. MODE 1: gate a' = (a + xc[row]*D) * silu(z[row]).
// MODE 2: LN-A — a' = (a - mean[row]) * rstd[row] * w[col] + b[col].
// MODE 3: conv-A — a' = silu(conv4(xz[.,col]) + cb[col]); writes a' to csb
//         (xc0 side output) and stages it (x_proj fusion; A arg unused).
// CSTAT 1: epilogue accumulates per-column sum/sumsq into csb (atomics).
#define SP 40
template<int BM, int BN, int MODE, int CSTAT>
__global__ __launch_bounds__(256) void gemm_mfma_kernel(
    const float* __restrict__ A, const float* __restrict__ B, float* __restrict__ C,
    int M, int N, int K, int lda, int ldb, int ldc,
    long long sA, long long sB_, long long sC_,
    int transB, int accsub,
    const float* __restrict__ gxc, const float* __restrict__ gxz, const float* __restrict__ gD,
    const float* __restrict__ rs, const float* __restrict__ cw2, const float* __restrict__ cb2,
    float* __restrict__ csb, int NFS)
{
    constexpr int WM = BM / 2, WN = BN / 2, MI = WM / 16, NI = WN / 16;
    __shared__ short As[BM * SP];
    __shared__ short Bs[BN * SP];
    int tid = threadIdx.x;
    int m0 = blockIdx.x * BM, n0 = blockIdx.y * BN;
    A += (long long)blockIdx.z * sA;
    B += (long long)blockIdx.z * sB_;
    C += (long long)blockIdx.z * sC_;
    int lane = tid & 63, wid = tid >> 6;
    int wr = wid >> 1, wc = wid & 1;
    int lr = lane & 15, lg = lane >> 4;
    f32x4 acc[MI][NI] = {};

    for (int k0 = 0; k0 < K; k0 += 32) {
#pragma unroll
        for (int it = 0; it < BM * 8 / 256; ++it) {
            int idx = tid + it * 256;
            int row = idx >> 3, kq = idx & 7;
            long long gm = m0 + row;
            float4 v;
            if (MODE == 3) {
                int t = (int)(gm & 511);
                int dcol = k0 + kq * 4;
                float4 r = *(const float4*)(cb2 + dcol);
#pragma unroll
                for (int kk = 0; kk < 4; ++kk) {
                    int tt = t + kk - 3;
                    if (tt >= 0) {
                        float4 xv = *(const float4*)(gxz + (gm + (long long)(kk - 3)) * 768 + dcol);
                        r.x = fmaf(xv.x, gD[(dcol + 0) * 4 + kk], r.x);
                        r.y = fmaf(xv.y, gD[(dcol + 1) * 4 + kk], r.y);
                        r.z = fmaf(xv.z, gD[(dcol + 2) * 4 + kk], r.z);
                        r.w = fmaf(xv.w, gD[(dcol + 3) * 4 + kk], r.w);
                    }
                }
                r.x = r.x * sigmoidf_(r.x);
                r.y = r.y * sigmoidf_(r.y);
                r.z = r.z * sigmoidf_(r.z);
                r.w = r.w * sigmoidf_(r.w);
                *(float4*)(csb + gm * 384 + dcol) = r;
                v = r;
            } else {
                v = *(const float4*)(A + gm * lda + k0 + kq * 4);
            }
            if (MODE == 1) {
                float4 xcv = *(const float4*)(gxc + gm * 384 + k0 + kq * 4);
                float4 zv  = *(const float4*)(gxz + gm * 768 + 384 + k0 + kq * 4);
                float4 Dv  = *(const float4*)(gD + k0 + kq * 4);
                v.x = (v.x + xcv.x * Dv.x) * (zv.x * sigmoidf_(zv.x));
                v.y = (v.y + xcv.y * Dv.y) * (zv.y * sigmoidf_(zv.y));
                v.z = (v.z + xcv.z * Dv.z) * (zv.z * sigmoidf_(zv.z));
                v.w = (v.w + xcv.w * Dv.w) * (zv.w * sigmoidf_(zv.w));
            }
            if (MODE == 2) {
                float2 st = *(const float2*)(rs + gm * 2);     // mean, rstd
                float4 wv = *(const float4*)(cw2 + k0 + kq * 4);
                float4 bv = *(const float4*)(cb2 + k0 + kq * 4);
                v.x = (v.x - st.x) * st.y * wv.x + bv.x;
                v.y = (v.y - st.x) * st.y * wv.y + bv.y;
                v.z = (v.z - st.x) * st.y * wv.z + bv.z;
                v.w = (v.w - st.x) * st.y * wv.w + bv.w;
            }
            short4 b4 = make_short4(f2bf(v.x), f2bf(v.y), f2bf(v.z), f2bf(v.w));
            *(short4*)(&As[row * SP + kq * 4]) = b4;
        }
        if (transB) {
#pragma unroll
            for (int it = 0; it < BN * 8 / 256; ++it) {
                int idx = tid + it * 256;
                int row = idx >> 3, kq = idx & 7;
                int gn = n0 + row;
                float4 v = make_float4(0.f, 0.f, 0.f, 0.f);
                if (gn < N) v = *(const float4*)(B + (long long)gn * ldb + k0 + kq * 4);
                short4 b4 = make_short4(f2bf(v.x), f2bf(v.y), f2bf(v.z), f2bf(v.w));
                *(short4*)(&Bs[row * SP + kq * 4]) = b4;
            }
        } else {
            constexpr int NQ = BN / 4;
#pragma unroll
            for (int it = 0; it < 32 * NQ / 256; ++it) {
                int idx = tid + it * 256;
                int k = idx / NQ, nq = idx % NQ;
                int gn = n0 + nq * 4;
                float4 v = make_float4(0.f, 0.f, 0.f, 0.f);
                if (gn < N) v = *(const float4*)(B + (long long)(k0 + k) * ldb + gn);
                Bs[(nq * 4 + 0) * SP + k] = f2bf(v.x);
                Bs[(nq * 4 + 1) * SP + k] = f2bf(v.y);
                Bs[(nq * 4 + 2) * SP + k] = f2bf(v.z);
                Bs[(nq * 4 + 3) * SP + k] = f2bf(v.w);
            }
        }
        __syncthreads();
        bshort8 af[MI], bfr[NI];
#pragma unroll
        for (int i = 0; i < MI; ++i)
            af[i] = *(const bshort8*)(&As[(wr * WM + i * 16 + lr) * SP + lg * 8]);
#pragma unroll
        for (int j = 0; j < NI; ++j)
            bfr[j] = *(const bshort8*)(&Bs[(wc * WN + j * 16 + lr) * SP + lg * 8]);
#pragma unroll
        for (int i = 0; i < MI; ++i)
#pragma unroll
            for (int j = 0; j < NI; ++j)
                acc[i][j] = __builtin_amdgcn_mfma_f32_16x16x32_bf16(af[i], bfr[j], acc[i][j], 0, 0, 0);
        __syncthreads();
    }
#pragma unroll
    for (int i = 0; i < MI; ++i) {
        int gm = m0 + wr * WM + i * 16 + lg * 4;
#pragma unroll
        for (int j = 0; j < NI; ++j) {
            int gn = n0 + wc * WN + j * 16 + lr;
            if (gn < N) {
#pragma unroll
                for (int r = 0; r < 4; ++r) {
                    long long idx = (long long)(gm + r) * ldc + gn;
                    float v = acc[i][j][r];
                    if (accsub) C[idx] = C[idx] - v;
                    else C[idx] = v;
                }
            }
        }
    }
    if (CSTAT) {
        float* red = (float*)As;   // reuse LDS: [wr][{s1,s2}][BN]
#pragma unroll
        for (int j = 0; j < NI; ++j) {
            float s1 = 0.f, s2 = 0.f;
#pragma unroll
            for (int i = 0; i < MI; ++i)
#pragma unroll
                for (int r = 0; r < 4; ++r) {
                    float v = acc[i][j][r];
                    s1 += v;
                    s2 += v * v;
                }
            s1 += __shfl_xor(s1, 16); s2 += __shfl_xor(s2, 16);
            s1 += __shfl_xor(s1, 32); s2 += __shfl_xor(s2, 32);
            if (lg == 0) {
                int col = wc * WN + j * 16 + lr;
                red[(wr * 2 + 0) * BN + col] = s1;
                red[(wr * 2 + 1) * BN + col] = s2;
            }
        }
        __syncthreads();
        if (tid < BN) {
            float s1 = red[0 * BN + tid] + red[2 * BN + tid];
            float s2 = red[1 * BN + tid] + red[3 * BN + tid];
            atomicAdd(&csb[n0 + tid], s1);
            atomicAdd(&csb[NFS + n0 + tid], s2);
        }
    }
}

// ---------------- prep: DFT tables (bf16) + x row-stats + stats zero ----------
__global__ __launch_bounds__(256) void prep_kernel(
    short* __restrict__ tc, short* __restrict__ ts,
    const float* __restrict__ x, float* __restrict__ rowstats,
    float* __restrict__ stats)
{
    int bid = blockIdx.x, tid = threadIdx.x;
    if (bid < 1024) {
        int idx = bid * 256 + tid;           // 512*512 table entries
        int k = idx >> 9, t = idx & 511;
        int r = (k * t) & 511;
        float th = (float)r * (6.283185307179586f / 512.f);
        float s, c;
        __sincosf(th, &s, &c);
        const float inv = 0.04419417382415922f;
        tc[idx] = f2bf(c * inv);
        ts[idx] = f2bf(s * inv);
    } else if (bid < 1088) {
        int rb = bid - 1024;                 // 64 blocks x 64 rows
        int lane = tid & 63, w = tid >> 6;
        for (int r = w; r < 64; r += 4) {
            long long row = (long long)rb * 64 + r;
            const float* xr = x + row * CDIM;
            float v0 = xr[lane], v1 = xr[lane + 64], v2 = xr[lane + 128];
            float s1 = v0 + v1 + v2;
            float s2 = v0 * v0 + v1 * v1 + v2 * v2;
#pragma unroll
            for (int off = 32; off >= 1; off >>= 1) {
                s1 += __shfl_xor(s1, off);
                s2 += __shfl_xor(s2, off);
            }
            if (lane == 0) {
                float mean = s1 * (1.f / 192.f);
                float var = s2 * (1.f / 192.f) - mean * mean;
                rowstats[row * 2] = mean;
                rowstats[row * 2 + 1] = rsqrtf(var + 1e-5f);
            }
        }
    } else {
#pragma unroll
        for (int i = 0; i < 8; ++i) stats[tid * 8 + i] = 0.f;
    }
}

// ---------------- DFT forward (real-fold: M=320 freq rows, K=512 time) -------
__global__ __launch_bounds__(256) void dft_fwd_kernel(
    const short* __restrict__ Tc, const short* __restrict__ Ts,
    const float* __restrict__ Bm, float* __restrict__ C1, float* __restrict__ C2,
    const float* __restrict__ stats, const float* __restrict__ bng,
    const float* __restrict__ bnb, float invM)
{
    __shared__ short Acs[64 * SP];
    __shared__ short Ass[64 * SP];
    __shared__ short Bs[64 * SP];
    int tid = threadIdx.x;
    int m0 = blockIdx.x * 64, n0 = blockIdx.y * 64;
    const float* B = Bm + (long long)blockIdx.z * 196608;
    float* c1 = C1 + (long long)blockIdx.z * 122880;
    float* c2 = C2 + (long long)blockIdx.z * 122880;
    int lane = tid & 63, wid = tid >> 6;
    int wr = wid >> 1, wc = wid & 1;
    int lr = lane & 15, lg = lane >> 4;
    int nn = tid & 63, k8 = tid >> 6;
    int f = n0 + nn;
    float sc, sh;
    {
        float m = stats[f] * invM;
        float vv = stats[384 + f] * invM - m * m;
        sc = rsqrtf(vv + 1e-5f) * bng[f];
        sh = bnb[f] - m * sc;
    }
    f32x4 a1[2][2] = {}, a2[2][2] = {};
    for (int k0 = 0; k0 < 512; k0 += 32) {
        {
            *(uint4*)(&Acs[nn * SP + k8 * 8]) =
                *(const uint4*)(Tc + (long long)(m0 + nn) * 512 + k0 + k8 * 8);
            *(uint4*)(&Ass[nn * SP + k8 * 8]) =
                *(const uint4*)(Ts + (long long)(m0 + nn) * 512 + k0 + k8 * 8);
        }
        {
            bshort8 pk;
#pragma unroll
            for (int j = 0; j < 8; ++j) {
                float v = B[(long long)(k0 + k8 * 8 + j) * 384 + f];
                v = fmaxf(fmaf(v, sc, sh), 0.f);
                pk[j] = f2bf(v);
            }
            *(bshort8*)(&Bs[nn * SP + k8 * 8]) = pk;
        }
        __syncthreads();
        bshort8 af[2], sf[2], bf[2];
#pragma unroll
        for (int i = 0; i < 2; ++i) {
            af[i] = *(const bshort8*)(&Acs[(wr * 32 + i * 16 + lr) * SP + lg * 8]);
            sf[i] = *(const bshort8*)(&Ass[(wr * 32 + i * 16 + lr) * SP + lg * 8]);
            bf[i] = *(const bshort8*)(&Bs[(wc * 32 + i * 16 + lr) * SP + lg * 8]);
        }
#pragma unroll
        for (int i = 0; i < 2; ++i)
#pragma unroll
            for (int j = 0; j < 2; ++j) {
                a1[i][j] = __builtin_amdgcn_mfma_f32_16x16x32_bf16(af[i], bf[j], a1[i][j], 0, 0, 0);
                a2[i][j] = __builtin_amdgcn_mfma_f32_16x16x32_bf16(sf[i], bf[j], a2[i][j], 0, 0, 0);
            }
        __syncthreads();
    }
#pragma unroll
    for (int i = 0; i < 2; ++i) {
        int gm = m0 + wr * 32 + i * 16 + lg * 4;
#pragma unroll
        for (int j = 0; j < 2; ++j) {
            int gn = n0 + wc * 32 + j * 16 + lr;
#pragma unroll
            for (int r = 0; r < 4; ++r) {
                c1[(long long)(gm + r) * 384 + gn] = a1[i][j][r];
                c2[(long long)(gm + r) * 384 + gn] = a2[i][j][r];
            }
        }
    }
}

// ---------------- DFT inverse (real-fold: K=288 covering k=0..256) -----------
__global__ __launch_bounds__(256) void dft_inv_kernel(
    const short* __restrict__ Tc, const short* __restrict__ Ts,
    const float* __restrict__ Br, const float* __restrict__ Bi,
    float* __restrict__ Co,
    const float* __restrict__ rw, const float* __restrict__ iw,
    const float* __restrict__ rbv, const float* __restrict__ ibv)
{
    __shared__ short Acs[64 * SP];
    __shared__ short Ans[64 * SP];
    __shared__ short Brs[64 * SP];
    __shared__ short Bis[64 * SP];
    int tid = threadIdx.x;
    int m0 = blockIdx.x * 64, n0 = blockIdx.y * 64;
    const float* br = Br + (long long)blockIdx.z * 122880;
    const float* bi = Bi + (long long)blockIdx.z * 122880;
    float* co = Co + (long long)blockIdx.z * 196608;
    int lane = tid & 63, wid = tid >> 6;
    int wr = wid >> 1, wc = wid & 1;
    int lr = lane & 15, lg = lane >> 4;
    int nn = tid & 63, k8 = tid >> 6;
    int f = n0 + nn;
    float rd = rw[(long long)f * 384 + f];
    float id = iw[(long long)f * 384 + f];
    float rbs = rbv[f], ibs = ibv[f];
    f32x4 acc[2][2] = {};
    for (int k0 = 0; k0 < 288; k0 += 32) {
        {
            *(uint4*)(&Acs[nn * SP + k8 * 8]) =
                *(const uint4*)(Tc + (long long)(m0 + nn) * 512 + k0 + k8 * 8);
            uint4 ps = *(const uint4*)(Ts + (long long)(m0 + nn) * 512 + k0 + k8 * 8);
            ps.x ^= 0x80008000u; ps.y ^= 0x80008000u; ps.z ^= 0x80008000u; ps.w ^= 0x80008000u;
            *(uint4*)(&Ans[nn * SP + k8 * 8]) = ps;
        }
        {
            bshort8 pr, pi;
#pragma unroll
            for (int j = 0; j < 8; ++j) {
                int kg = k0 + k8 * 8 + j;
                short vr = 0, vi = 0;
                if (kg <= 256) {
                    float Re = br[(long long)kg * 384 + f];
                    float S  = bi[(long long)kg * 384 + f];
                    float wgt = (kg == 0 || kg == 256) ? 0.5f : 1.f;
                    float t1 = Re * rd + rbs, t2 = S * id;
                    float t3 = Re * id + ibs, t4 = S * rd;
                    float Rs = wgt * (fmaxf(t1 + t2, 0.f) + fmaxf(t1 - t2, 0.f));
                    float Is = wgt * (fmaxf(t3 - t4, 0.f) - fmaxf(t3 + t4, 0.f));
                    vr = f2bf(Rs);
                    vi = f2bf(Is);
                }
                pr[j] = vr;
                pi[j] = vi;
            }
            *(bshort8*)(&Brs[nn * SP + k8 * 8]) = pr;
            *(bshort8*)(&Bis[nn * SP + k8 * 8]) = pi;
        }
        __syncthreads();
        bshort8 af[2], nf[2], rf[2], iff[2];
#pragma unroll
        for (int i = 0; i < 2; ++i) {
            af[i]  = *(const bshort8*)(&Acs[(wr * 32 + i * 16 + lr) * SP + lg * 8]);
            nf[i]  = *(const bshort8*)(&Ans[(wr * 32 + i * 16 + lr) * SP + lg * 8]);
            rf[i]  = *(const bshort8*)(&Brs[(wc * 32 + i * 16 + lr) * SP + lg * 8]);
            iff[i] = *(const bshort8*)(&Bis[(wc * 32 + i * 16 + lr) * SP + lg * 8]);
        }
#pragma unroll
        for (int i = 0; i < 2; ++i)
#pragma unroll
            for (int j = 0; j < 2; ++j) {
                acc[i][j] = __builtin_amdgcn_mfma_f32_16x16x32_bf16(af[i], rf[j], acc[i][j], 0, 0, 0);
                acc[i][j] = __builtin_amdgcn_mfma_f32_16x16x32_bf16(nf[i], iff[j], acc[i][j], 0, 0, 0);
            }
        __syncthreads();
    }
#pragma unroll
    for (int i = 0; i < 2; ++i) {
        int gm = m0 + wr * 32 + i * 16 + lg * 4;
#pragma unroll
        for (int j = 0; j < 2; ++j) {
            int gn = n0 + wc * 32 + j * 16 + lr;
#pragma unroll
            for (int r = 0; r < 4; ++r)
                co[(long long)(gm + r) * 384 + gn] = acc[i][j][r];
        }
    }
}

// ---------------- scan pass 1: unique 32-chunk local scans -------------------
__global__ __launch_bounds__(256) void scan_pass1(
    const float* __restrict__ xdbl0, const float* __restrict__ xc0,
    const float* __restrict__ dt_w, const float* __restrict__ dt_b,
    const float* __restrict__ A_log, float* __restrict__ ylocal,
    float* __restrict__ hpart, float* __restrict__ sumdt, float* __restrict__ cumdtg)
{
    int d0 = blockIdx.x * 32, bb = blockIdx.y, c = blockIdx.z;
    __shared__ float sBC[LCH][96];
    __shared__ unsigned sdd[LCH][32];
    __shared__ float sdtl[LCH][12];
    __shared__ float sdtw[32][12];
    __shared__ float sdtb[32];
    int tid = threadIdx.x;
    int p = tid >> 3, q = tid & 7, d = d0 + p;
    for (int i = tid; i < 384; i += 256) sdtw[i / 12][i % 12] = dt_w[(d0 + i / 12) * 12 + i % 12];
    if (tid < 32) sdtb[tid] = dt_b[d0 + tid];
    float A0 = -__expf(A_log[d * NST + 6 * q]);
    float Ad = -__expf(A_log[d * NST + 6 * q + 1]) - A0;
    long long srcbase = (long long)bb * LSEQ + c * LCH;
    for (int i = tid; i < LCH * 108; i += 256) {
        int tt = i / 108, cc = i % 108;
        float v = xdbl0[(srcbase + tt) * 108 + cc];
        if (cc < 12) sdtl[tt][cc] = v;
        else if (cc < 60) { int n = cc - 12; int qq = (n * 43) >> 8; sBC[tt][qq * 12 + (n - qq * 6)] = v; }
        else              { int n = cc - 60; int qq = (n * 43) >> 8; sBC[tt][qq * 12 + 6 + (n - qq * 6)] = v; }
    }
    __syncthreads();
    for (int i = tid; i < LCH * 32; i += 256) {
        int tt = i >> 5, j = i & 31;
        float s = sdtb[j];
#pragma unroll
        for (int r = 0; r < 12; ++r) s = fmaf(sdtl[tt][r], sdtw[j][r], s);
        s = fmaxf(s, 0.f) + log1pf(__expf(-fabsf(s)));
        float u = xc0[(srcbase + tt) * DIN + d0 + j];
        unsigned hi = (unsigned)(unsigned short)f2bf(s);
        unsigned lo = (unsigned)(unsigned short)f2bf(s * u);
        sdd[tt][j] = (hi << 16) | lo;
    }
    __syncthreads();
    float h0r = 0.f, h1r = 0.f, h2r = 0.f, h3r = 0.f, h4r = 0.f, h5r = 0.f;
    float cum = 0.f;
#pragma unroll 2
    for (int tt = 0; tt < LCH; ++tt) {
        unsigned pk = sdd[tt][p];
        float s = bfhi2f(pk), du = bflo2f(pk);
        cum += s;
        float f = __expf(s * A0);
        float w = __expf(s * Ad);
        float4 v0 = *(const float4*)&sBC[tt][q * 12];
        float4 v1 = *(const float4*)&sBC[tt][q * 12 + 4];
        float4 v2 = *(const float4*)&sBC[tt][q * 12 + 8];
        float y;
        h0r = fmaf(f, h0r, du * v0.x); y = h0r * v1.z;          f *= w;
        h1r = fmaf(f, h1r, du * v0.y); y = fmaf(h1r, v1.w, y);  f *= w;
        h2r = fmaf(f, h2r, du * v0.z); y = fmaf(h2r, v2.x, y);  f *= w;
        h3r = fmaf(f, h3r, du * v0.w); y = fmaf(h3r, v2.y, y);  f *= w;
        h4r = fmaf(f, h4r, du * v1.x); y = fmaf(h4r, v2.z, y);  f *= w;
        h5r = fmaf(f, h5r, du * v1.y); y = fmaf(h5r, v2.w, y);
        y += __shfl_xor(y, 1);
        y += __shfl_xor(y, 2);
        y += __shfl_xor(y, 4);
        if (q == 0) {
            ylocal[(srcbase + tt) * DIN + d] = y;
            cumdtg[(srcbase + tt) * DIN + d] = cum;
        }
    }
    if (q == 0) sumdt[((long long)(bb * NCH + c)) * DIN + d] = cum;
    float* hp = &hpart[(((long long)(bb * NCH + c)) * DIN + d) * NST + 6 * q];
    hp[0] = h0r; hp[1] = h1r; hp[2] = h2r; hp[3] = h3r; hp[4] = h4r; hp[5] = h5r;
}

// ---------------- scan pass 2: averaged incoming states hbar(c) --------------
__global__ __launch_bounds__(256) void scan_pass2(
    const float* __restrict__ A_log, const float* __restrict__ sumdt,
    const float* __restrict__ hpart, float* __restrict__ hbarb)
{
    long long idx = (long long)blockIdx.x * 256 + threadIdx.x;  // 8*384*48
    if (idx >= 8LL * DIN * NST) return;
    int n = (int)(idx % NST);
    long long rem = idx / NST;
    int d = (int)(rem % DIN);
    int bb = (int)(rem / DIN);
    float An = -__expf(A_log[d * NST + n]);
    float G = 0.f;
#pragma unroll
    for (int c = 0; c < NCH; ++c) {
        float nc = (float)((c >> 2) + 1);
        hbarb[(((long long)(bb * NCH + c)) * DIN + d) * NST + n] = G / nc;
        float S = hpart[(((long long)(bb * NCH + c)) * DIN + d) * NST + n];
        float P = __expf(An * sumdt[((long long)(bb * NCH + c)) * DIN + d]);
        G = fmaf(P, G, nc * S);
    }
}

// ---------------- scan pass 3: ybar = ylocal + C.(exp(A*cumdt)*hbar) ---------
#define TT3 16
__global__ __launch_bounds__(256) void scan_pass3(
    const float* __restrict__ xdbl0, const float* __restrict__ cumdtg,
    const float* __restrict__ A_log, const float* __restrict__ hbarb,
    float* __restrict__ ylocal)
{
    int c = blockIdx.z >> 1, tq = blockIdx.z & 1;
    int toff = tq * TT3;
    int d0 = blockIdx.x * 32, bb = blockIdx.y;
    __shared__ float sC[TT3][64];
    __shared__ float scum[TT3][32];
    int tid = threadIdx.x;
    int p = tid >> 3, q = tid & 7, d = d0 + p;
    float A0 = -__expf(A_log[d * NST + 6 * q]);
    float Ad = -__expf(A_log[d * NST + 6 * q + 1]) - A0;
    float g0[6];
    {
        const float* hp0 = &hbarb[(((long long)(bb * NCH + c)) * DIN + d) * NST + 6 * q];
#pragma unroll
        for (int k = 0; k < 6; ++k) g0[k] = hp0[k];
    }
    long long srcbase = (long long)bb * LSEQ + c * LCH + toff;
    for (int i = tid; i < TT3 * 48; i += 256) {
        int tt = i / 48, n = i % 48;
        int qq = (n * 43) >> 8;
        sC[tt][qq * 8 + n - qq * 6] = xdbl0[(srcbase + tt) * 108 + 60 + n];
    }
    for (int i = tid; i < TT3 * 32; i += 256) {
        int tt = i >> 5, j = i & 31;
        scum[tt][j] = cumdtg[(srcbase + tt) * DIN + d0 + j];
    }
    __syncthreads();
#pragma unroll 2
    for (int tt = 0; tt < TT3; ++tt) {
        float cd = scum[tt][p];
        float f = __expf(cd * A0);
        float w = __expf(cd * Ad);
        float4 c03 = *(const float4*)&sC[tt][q * 8];
        float4 c45 = *(const float4*)&sC[tt][q * 8 + 4];
        float a0;
        a0 = c03.x * g0[0] * f;            f *= w;
        a0 = fmaf(c03.y * g0[1], f, a0);   f *= w;
        a0 = fmaf(c03.z * g0[2], f, a0);   f *= w;
        a0 = fmaf(c03.w * g0[3], f, a0);   f *= w;
        a0 = fmaf(c45.x * g0[4], f, a0);   f *= w;
        a0 = fmaf(c45.y * g0[5], f, a0);
        a0 += __shfl_xor(a0, 1); a0 += __shfl_xor(a0, 2); a0 += __shfl_xor(a0, 4);
        if (q == 0) {
            long long yi = (srcbase + tt) * DIN + d;
            ylocal[yi] = ylocal[yi] + a0;
        }
    }
}

// ---------------- LN(norm1) + residual -> x1 + rowstats2 ---------------------
__global__ __launch_bounds__(64) void combine_ln_kernel(
    const float* __restrict__ ym, const float* __restrict__ x,
    const float* __restrict__ w, const float* __restrict__ b,
    float* __restrict__ x1, float* __restrict__ rowstats2)
{
    int row = blockIdx.x;
    int lane = threadIdx.x;
    long long base = (long long)row * CDIM;
    float vals[3];
#pragma unroll
    for (int cp = 0; cp < 3; ++cp) vals[cp] = ym[base + lane + cp * 64];
    float s1 = vals[0] + vals[1] + vals[2];
    float s2 = vals[0] * vals[0] + vals[1] * vals[1] + vals[2] * vals[2];
#pragma unroll
    for (int off = 32; off >= 1; off >>= 1) {
        s1 += __shfl_xor(s1, off);
        s2 += __shfl_xor(s2, off);
    }
    float mean = s1 * (1.f / 192.f);
    float var = s2 * (1.f / 192.f) - mean * mean;
    float rstd = rsqrtf(var + 1e-5f);
    float xv[3];
#pragma unroll
    for (int cp = 0; cp < 3; ++cp) {
        int c = lane + cp * 64;
        xv[cp] = x[base + c] + (vals[cp] - mean) * rstd * w[c] + b[c];
        x1[base + c] = xv[cp];
    }
    float t1 = xv[0] + xv[1] + xv[2];
    float t2 = xv[0] * xv[0] + xv[1] * xv[1] + xv[2] * xv[2];
#pragma unroll
    for (int off = 32; off >= 1; off >>= 1) {
        t1 += __shfl_xor(t1, off);
        t2 += __shfl_xor(t2, off);
    }
    if (lane == 0) {
        float mean2 = t1 * (1.f / 192.f);
        float var2 = t2 * (1.f / 192.f) - mean2 * mean2;
        rowstats2[row * 2] = mean2;
        rowstats2[row * 2 + 1] = rsqrtf(var2 + 1e-5f);
    }
}

// ---------------- batchnorm apply (final, with residual) ----------------
__global__ __launch_bounds__(256) void bnapply_kernel(
    const float* __restrict__ X, const float* __restrict__ stats,
    const float* __restrict__ g, const float* __restrict__ b,
    const float* __restrict__ residual, float* __restrict__ out,
    int NF, int relu, float invM)
{
    long long idx = (long long)blockIdx.x * 256 + threadIdx.x;
    int f = (int)(idx % NF);
    float mean = stats[f] * invM;
    float var = stats[NF + f] * invM - mean * mean;
    float v = (X[idx] - mean) * rsqrtf(var + 1e-5f) * g[f] + b[f];
    if (relu) v = fmaxf(v, 0.f);
    if (residual) v += residual[idx];
    out[idx] = v;
}

extern "C" void kernel_launch(void* const* d_in, const int* in_sizes, int n_in,
                              void* d_out, int out_size, void* d_ws, size_t ws_size,
                              hipStream_t stream)
{
    const float* x        = (const float*)d_in[0];
    const float* in_w     = (const float*)d_in[1];
    const float* conv_w   = (const float*)d_in[2];
    const float* conv_b   = (const float*)d_in[3];
    const float* xproj_w  = (const float*)d_in[4];
    const float* dtp_w    = (const float*)d_in[5];
    const float* dtp_b    = (const float*)d_in[6];
    const float* A_log    = (const float*)d_in[7];
    const float* D_par    = (const float*)d_in[8];
    const float* outp_w   = (const float*)d_in[9];
    const float* mnw      = (const float*)d_in[10];
    const float* mnb      = (const float*)d_in[11];
    const float* n1w      = (const float*)d_in[12];
    const float* n1b      = (const float*)d_in[13];
    const float* n2w      = (const float*)d_in[14];
    const float* n2b      = (const float*)d_in[15];
    const float* fc1_w    = (const float*)d_in[16];
    const float* bn1g     = (const float*)d_in[17];
    const float* bn1b     = (const float*)d_in[18];
    const float* r_w      = (const float*)d_in[19];
    const float* i_w      = (const float*)d_in[20];
    const float* rb       = (const float*)d_in[21];
    const float* ib       = (const float*)d_in[22];
    const float* fc2_w    = (const float*)d_in[23];
    const float* bn2g     = (const float*)d_in[24];
    const float* bn2b     = (const float*)d_in[25];
    float* out = (float*)d_out;
    float* ws = (float*)d_ws;

    // workspace (floats)
    float* x1pad  = ws;                        //  786432
    float* xz0    = x1pad  + 786432LL;         // 3145728 (z dead after out_proj)
    float* xc0    = xz0    + 3145728LL;        // 1572864 (dead after out_proj)
    float* xdbl0  = xc0    + 1572864LL;        //  442368 (dead after pass3)
    float* ylocal = xdbl0  + 442368LL;         // 1572864 (pass1->pass3->out_proj A)
    float* hbarb  = ylocal + 1572864LL;        // 2359296 (pass2->pass3)
    float* cumdtg = hbarb  + 2359296LL;        // 1572864 (pass1->pass3)
    float* hpart  = cumdtg + 1572864LL;        // 2359296 (pass1->pass2)
    float* sumdt  = hpart  + 2359296LL;        //   49152
    // dedicated (never aliased) regions:
    float* rowst1 = sumdt  + 49152LL;          //    8192 (x row stats)
    float* rowst2 = rowst1 + 8192LL;           //    8192 (x1 row stats)
    float* stats  = rowst2 + 8192LL;           //    2048 (bn1 @0, bn2 @1024)
    short* tabc_bf = (short*)(stats + 2048LL); //  262144 shorts
    short* tabs_bf = tabc_bf + 262144LL;       //  262144 shorts
    // aliases (after the producer is dead):
    float* ymout = hbarb;                      //  786432 <= 2359296 (after pass3)
    float* x1    = x1pad;
    float* hbuf  = xz0;                        // 1572864 (xz0 dead after out_proj)
    float* hfr   = xz0 + 1572864LL;            //  983040 (320x384x8)
    float* hfi   = xc0;                        //  983040 (xc0 dead after out_proj)
    float* xt    = ylocal;                     // 1572864 (ylocal dead after out_proj)
    float* g0    = hpart;                      //  786432 (hpart dead after pass2)

    // 0. prep: DFT tables + x row-stats + stats zero
    prep_kernel<<<dim3(1089), dim3(256), 0, stream>>>(tabc_bf, tabs_bf, x, rowst1, stats);

    // 2. in_proj with fused mnorm LN: xz0 = LN(x) @ in_w^T  M=4096 N=768 K=192
    gemm_mfma_kernel<64, 128, 2, 0><<<dim3(64, 6, 1), dim3(256), 0, stream>>>(
        x, in_w, xz0, 4096, 768, 192, 192, 192, 768, 0, 0, 0, 1, 0,
        nullptr, nullptr, nullptr, rowst1, mnw, mnb, nullptr, 0);

    // 3+4. x_proj with fused conv+silu A-staging (writes xc0 side output):
    //      xdbl0 = silu(conv(xz0)) @ xproj_w^T   M=4096 N=108 K=384
    gemm_mfma_kernel<64, 64, 3, 0><<<dim3(64, 2, 1), dim3(256), 0, stream>>>(
        nullptr, xproj_w, xdbl0, 4096, 108, 384, 384, 384, 108, 0, 0, 0, 1, 0,
        nullptr, xz0, conv_w, nullptr, nullptr, conv_b, xc0, 0);

    // 5. selective scan
    scan_pass1<<<dim3(12, 8, NCH), dim3(256), 0, stream>>>(
        xdbl0, xc0, dtp_w, dtp_b, A_log, ylocal, hpart, sumdt, cumdtg);
    scan_pass2<<<dim3(576), dim3(256), 0, stream>>>(A_log, sumdt, hpart, hbarb);
    scan_pass3<<<dim3(12, 8, NCH * 2), dim3(256), 0, stream>>>(
        xdbl0, cumdtg, A_log, hbarb, ylocal);

    // 6+7. out_proj with fused gate on averaged y: M=4096
    gemm_mfma_kernel<32, 64, 1, 0><<<dim3(128, 3, 1), dim3(256), 0, stream>>>(
        ylocal, outp_w, ymout, 4096, 192, 384, 384, 384, 192, 0, 0, 0, 1, 0,
        xc0, xz0, D_par, nullptr, nullptr, nullptr, nullptr, 0);

    // 8+9. LN(norm1) + residual -> x1 + row stats for norm2
    combine_ln_kernel<<<dim3(NB * LSEQ), dim3(64), 0, stream>>>(
        ymout, x, n1w, n1b, x1, rowst2);

    // 10+11. fc1 with fused norm2 LN + fused bn1 column stats
    gemm_mfma_kernel<64, 64, 2, 1><<<dim3(64, 6, 1), dim3(256), 0, stream>>>(
        x1, fc1_w, hbuf, 4096, 384, 192, 192, 192, 384, 0, 0, 0, 1, 0,
        nullptr, nullptr, nullptr, rowst2, n2w, n2b, stats, 384);

    // 13. forward DFT: k=0..319 freq rows (real-input fold), bn1 fused
    dft_fwd_kernel<<<dim3(5, 6, 8), dim3(256), 0, stream>>>(
        tabc_bf, tabs_bf, hbuf, hfr, hfi, stats, bn1g, bn1b, 1.f / 4096.f);

    // 14+15. inverse DFT: K=288 (folded), freq diag+bias+relu fused
    dft_inv_kernel<<<dim3(8, 6, 8), dim3(256), 0, stream>>>(
        tabc_bf, tabs_bf, hfr, hfi, xt, r_w, i_w, rb, ib);

    // 16+17a. fc2 with fused bn2 column stats
    gemm_mfma_kernel<32, 64, 0, 1><<<dim3(128, 3, 1), dim3(256), 0, stream>>>(
        xt, fc2_w, g0, 4096, 192, 384, 384, 384, 192, 0, 0, 0, 1, 0,
        nullptr, nullptr, nullptr, nullptr, nullptr, nullptr, stats + 1024, 192);

    // 17b. bn2 apply + residual -> out
    bnapply_kernel<<<dim3(3072), dim3(256), 0, stream>>>(
        g0, stats + 1024, bn2g, bn2b, x1, out, 192, 0, 1.f / 4096.f);
}

// Round 18
// 223.821 us; speedup vs baseline: 1.1016x; 1.1016x over previous
//
#include <hip/hip_runtime.h>
#include <math.h>

#define LSEQ 512
#define CDIM 192
#define DIN  384
#define NST  48
#define RNK  12
#define NB   8
#define NCH  16   // scan chunks (32 long)
#define LCH  32   // chunk length

static __device__ __forceinline__ float sigmoidf_(float x) { return 1.f / (1.f + __expf(-x)); }

typedef __attribute__((ext_vector_type(8))) short bshort8;
typedef __attribute__((ext_vector_type(4))) float f32x4;

static __device__ __forceinline__ short f2bf(float x) {
    unsigned u = __float_as_uint(x);
    unsigned r = (u + 0x7FFFu + ((u >> 16) & 1u)) >> 16;   // RNE
    return (short)r;
}
static __device__ __forceinline__ float bfhi2f(unsigned pk) { return __uint_as_float(pk & 0xffff0000u); }
static __device__ __forceinline__ float bflo2f(unsigned pk) { return __uint_as_float(pk << 16); }

// ---------------- bf16 MFMA GEMM (tile-templated) ----------------
// MODE 0: plain. MODE 1: gate a' = (a + xc[row]*D) * silu(z[row]).
// MODE 2: LN-A — a' = (a - mean[row]) * rstd[row] * w[col] + b[col].
// CSTAT 1: epilogue accumulates per-column sum/sumsq into csb (atomics).
// NOTE round-17 lesson: do NOT fuse long-latency producer work (conv) into
// A-staging on small grids — latency serialization (50us vs 18us split).
#define SP 40
template<int BM, int BN, int MODE, int CSTAT>
__global__ __launch_bounds__(256) void gemm_mfma_kernel(
    const float* __restrict__ A, const float* __restrict__ B, float* __restrict__ C,
    int M, int N, int K, int lda, int ldb, int ldc,
    long long sA, long long sB_, long long sC_,
    int transB, int accsub,
    const float* __restrict__ gxc, const float* __restrict__ gxz, const float* __restrict__ gD,
    const float* __restrict__ rs, const float* __restrict__ cw2, const float* __restrict__ cb2,
    float* __restrict__ csb, int NFS)
{
    constexpr int WM = BM / 2, WN = BN / 2, MI = WM / 16, NI = WN / 16;
    __shared__ short As[BM * SP];
    __shared__ short Bs[BN * SP];
    int tid = threadIdx.x;
    int m0 = blockIdx.x * BM, n0 = blockIdx.y * BN;
    A += (long long)blockIdx.z * sA;
    B += (long long)blockIdx.z * sB_;
    C += (long long)blockIdx.z * sC_;
    int lane = tid & 63, wid = tid >> 6;
    int wr = wid >> 1, wc = wid & 1;
    int lr = lane & 15, lg = lane >> 4;
    f32x4 acc[MI][NI] = {};

    for (int k0 = 0; k0 < K; k0 += 32) {
#pragma unroll
        for (int it = 0; it < BM * 8 / 256; ++it) {
            int idx = tid + it * 256;
            int row = idx >> 3, kq = idx & 7;
            long long gm = m0 + row;
            float4 v = *(const float4*)(A + gm * lda + k0 + kq * 4);
            if (MODE == 1) {
                float4 xcv = *(const float4*)(gxc + gm * 384 + k0 + kq * 4);
                float4 zv  = *(const float4*)(gxz + gm * 768 + 384 + k0 + kq * 4);
                float4 Dv  = *(const float4*)(gD + k0 + kq * 4);
                v.x = (v.x + xcv.x * Dv.x) * (zv.x * sigmoidf_(zv.x));
                v.y = (v.y + xcv.y * Dv.y) * (zv.y * sigmoidf_(zv.y));
                v.z = (v.z + xcv.z * Dv.z) * (zv.z * sigmoidf_(zv.z));
                v.w = (v.w + xcv.w * Dv.w) * (zv.w * sigmoidf_(zv.w));
            }
            if (MODE == 2) {
                float2 st = *(const float2*)(rs + gm * 2);     // mean, rstd
                float4 wv = *(const float4*)(cw2 + k0 + kq * 4);
                float4 bv = *(const float4*)(cb2 + k0 + kq * 4);
                v.x = (v.x - st.x) * st.y * wv.x + bv.x;
                v.y = (v.y - st.x) * st.y * wv.y + bv.y;
                v.z = (v.z - st.x) * st.y * wv.z + bv.z;
                v.w = (v.w - st.x) * st.y * wv.w + bv.w;
            }
            short4 b4 = make_short4(f2bf(v.x), f2bf(v.y), f2bf(v.z), f2bf(v.w));
            *(short4*)(&As[row * SP + kq * 4]) = b4;
        }
        if (transB) {
#pragma unroll
            for (int it = 0; it < BN * 8 / 256; ++it) {
                int idx = tid + it * 256;
                int row = idx >> 3, kq = idx & 7;
                int gn = n0 + row;
                float4 v = make_float4(0.f, 0.f, 0.f, 0.f);
                if (gn < N) v = *(const float4*)(B + (long long)gn * ldb + k0 + kq * 4);
                short4 b4 = make_short4(f2bf(v.x), f2bf(v.y), f2bf(v.z), f2bf(v.w));
                *(short4*)(&Bs[row * SP + kq * 4]) = b4;
            }
        } else {
            constexpr int NQ = BN / 4;
#pragma unroll
            for (int it = 0; it < 32 * NQ / 256; ++it) {
                int idx = tid + it * 256;
                int k = idx / NQ, nq = idx % NQ;
                int gn = n0 + nq * 4;
                float4 v = make_float4(0.f, 0.f, 0.f, 0.f);
                if (gn < N) v = *(const float4*)(B + (long long)(k0 + k) * ldb + gn);
                Bs[(nq * 4 + 0) * SP + k] = f2bf(v.x);
                Bs[(nq * 4 + 1) * SP + k] = f2bf(v.y);
                Bs[(nq * 4 + 2) * SP + k] = f2bf(v.z);
                Bs[(nq * 4 + 3) * SP + k] = f2bf(v.w);
            }
        }
        __syncthreads();
        bshort8 af[MI], bfr[NI];
#pragma unroll
        for (int i = 0; i < MI; ++i)
            af[i] = *(const bshort8*)(&As[(wr * WM + i * 16 + lr) * SP + lg * 8]);
#pragma unroll
        for (int j = 0; j < NI; ++j)
            bfr[j] = *(const bshort8*)(&Bs[(wc * WN + j * 16 + lr) * SP + lg * 8]);
#pragma unroll
        for (int i = 0; i < MI; ++i)
#pragma unroll
            for (int j = 0; j < NI; ++j)
                acc[i][j] = __builtin_amdgcn_mfma_f32_16x16x32_bf16(af[i], bfr[j], acc[i][j], 0, 0, 0);
        __syncthreads();
    }
#pragma unroll
    for (int i = 0; i < MI; ++i) {
        int gm = m0 + wr * WM + i * 16 + lg * 4;
#pragma unroll
        for (int j = 0; j < NI; ++j) {
            int gn = n0 + wc * WN + j * 16 + lr;
            if (gn < N) {
#pragma unroll
                for (int r = 0; r < 4; ++r) {
                    long long idx = (long long)(gm + r) * ldc + gn;
                    float v = acc[i][j][r];
                    if (accsub) C[idx] = C[idx] - v;
                    else C[idx] = v;
                }
            }
        }
    }
    if (CSTAT) {
        float* red = (float*)As;   // reuse LDS: [wr][{s1,s2}][BN]
#pragma unroll
        for (int j = 0; j < NI; ++j) {
            float s1 = 0.f, s2 = 0.f;
#pragma unroll
            for (int i = 0; i < MI; ++i)
#pragma unroll
                for (int r = 0; r < 4; ++r) {
                    float v = acc[i][j][r];
                    s1 += v;
                    s2 += v * v;
                }
            s1 += __shfl_xor(s1, 16); s2 += __shfl_xor(s2, 16);
            s1 += __shfl_xor(s1, 32); s2 += __shfl_xor(s2, 32);
            if (lg == 0) {
                int col = wc * WN + j * 16 + lr;
                red[(wr * 2 + 0) * BN + col] = s1;
                red[(wr * 2 + 1) * BN + col] = s2;
            }
        }
        __syncthreads();
        if (tid < BN) {
            float s1 = red[0 * BN + tid] + red[2 * BN + tid];
            float s2 = red[1 * BN + tid] + red[3 * BN + tid];
            atomicAdd(&csb[n0 + tid], s1);
            atomicAdd(&csb[NFS + n0 + tid], s2);
        }
    }
}

// ---------------- prep: DFT tables (bf16) + x row-stats + stats zero ----------
__global__ __launch_bounds__(256) void prep_kernel(
    short* __restrict__ tc, short* __restrict__ ts,
    const float* __restrict__ x, float* __restrict__ rowstats,
    float* __restrict__ stats)
{
    int bid = blockIdx.x, tid = threadIdx.x;
    if (bid < 1024) {
        int idx = bid * 256 + tid;           // 512*512 table entries
        int k = idx >> 9, t = idx & 511;
        int r = (k * t) & 511;
        float th = (float)r * (6.283185307179586f / 512.f);
        float s, c;
        __sincosf(th, &s, &c);
        const float inv = 0.04419417382415922f;
        tc[idx] = f2bf(c * inv);
        ts[idx] = f2bf(s * inv);
    } else if (bid < 1088) {
        int rb = bid - 1024;                 // 64 blocks x 64 rows
        int lane = tid & 63, w = tid >> 6;
        for (int r = w; r < 64; r += 4) {
            long long row = (long long)rb * 64 + r;
            const float* xr = x + row * CDIM;
            float v0 = xr[lane], v1 = xr[lane + 64], v2 = xr[lane + 128];
            float s1 = v0 + v1 + v2;
            float s2 = v0 * v0 + v1 * v1 + v2 * v2;
#pragma unroll
            for (int off = 32; off >= 1; off >>= 1) {
                s1 += __shfl_xor(s1, off);
                s2 += __shfl_xor(s2, off);
            }
            if (lane == 0) {
                float mean = s1 * (1.f / 192.f);
                float var = s2 * (1.f / 192.f) - mean * mean;
                rowstats[row * 2] = mean;
                rowstats[row * 2 + 1] = rsqrtf(var + 1e-5f);
            }
        }
    } else {
#pragma unroll
        for (int i = 0; i < 8; ++i) stats[tid * 8 + i] = 0.f;
    }
}

// ---------------- DFT forward (real-fold: M=320 freq rows, K=512 time) -------
__global__ __launch_bounds__(256) void dft_fwd_kernel(
    const short* __restrict__ Tc, const short* __restrict__ Ts,
    const float* __restrict__ Bm, float* __restrict__ C1, float* __restrict__ C2,
    const float* __restrict__ stats, const float* __restrict__ bng,
    const float* __restrict__ bnb, float invM)
{
    __shared__ short Acs[64 * SP];
    __shared__ short Ass[64 * SP];
    __shared__ short Bs[64 * SP];
    int tid = threadIdx.x;
    int m0 = blockIdx.x * 64, n0 = blockIdx.y * 64;
    const float* B = Bm + (long long)blockIdx.z * 196608;
    float* c1 = C1 + (long long)blockIdx.z * 122880;
    float* c2 = C2 + (long long)blockIdx.z * 122880;
    int lane = tid & 63, wid = tid >> 6;
    int wr = wid >> 1, wc = wid & 1;
    int lr = lane & 15, lg = lane >> 4;
    int nn = tid & 63, k8 = tid >> 6;
    int f = n0 + nn;
    float sc, sh;
    {
        float m = stats[f] * invM;
        float vv = stats[384 + f] * invM - m * m;
        sc = rsqrtf(vv + 1e-5f) * bng[f];
        sh = bnb[f] - m * sc;
    }
    f32x4 a1[2][2] = {}, a2[2][2] = {};
    for (int k0 = 0; k0 < 512; k0 += 32) {
        {
            *(uint4*)(&Acs[nn * SP + k8 * 8]) =
                *(const uint4*)(Tc + (long long)(m0 + nn) * 512 + k0 + k8 * 8);
            *(uint4*)(&Ass[nn * SP + k8 * 8]) =
                *(const uint4*)(Ts + (long long)(m0 + nn) * 512 + k0 + k8 * 8);
        }
        {
            bshort8 pk;
#pragma unroll
            for (int j = 0; j < 8; ++j) {
                float v = B[(long long)(k0 + k8 * 8 + j) * 384 + f];
                v = fmaxf(fmaf(v, sc, sh), 0.f);
                pk[j] = f2bf(v);
            }
            *(bshort8*)(&Bs[nn * SP + k8 * 8]) = pk;
        }
        __syncthreads();
        bshort8 af[2], sf[2], bf[2];
#pragma unroll
        for (int i = 0; i < 2; ++i) {
            af[i] = *(const bshort8*)(&Acs[(wr * 32 + i * 16 + lr) * SP + lg * 8]);
            sf[i] = *(const bshort8*)(&Ass[(wr * 32 + i * 16 + lr) * SP + lg * 8]);
            bf[i] = *(const bshort8*)(&Bs[(wc * 32 + i * 16 + lr) * SP + lg * 8]);
        }
#pragma unroll
        for (int i = 0; i < 2; ++i)
#pragma unroll
            for (int j = 0; j < 2; ++j) {
                a1[i][j] = __builtin_amdgcn_mfma_f32_16x16x32_bf16(af[i], bf[j], a1[i][j], 0, 0, 0);
                a2[i][j] = __builtin_amdgcn_mfma_f32_16x16x32_bf16(sf[i], bf[j], a2[i][j], 0, 0, 0);
            }
        __syncthreads();
    }
#pragma unroll
    for (int i = 0; i < 2; ++i) {
        int gm = m0 + wr * 32 + i * 16 + lg * 4;
#pragma unroll
        for (int j = 0; j < 2; ++j) {
            int gn = n0 + wc * 32 + j * 16 + lr;
#pragma unroll
            for (int r = 0; r < 4; ++r) {
                c1[(long long)(gm + r) * 384 + gn] = a1[i][j][r];
                c2[(long long)(gm + r) * 384 + gn] = a2[i][j][r];
            }
        }
    }
}

// ---------------- DFT inverse (real-fold: K=288 covering k=0..256) -----------
__global__ __launch_bounds__(256) void dft_inv_kernel(
    const short* __restrict__ Tc, const short* __restrict__ Ts,
    const float* __restrict__ Br, const float* __restrict__ Bi,
    float* __restrict__ Co,
    const float* __restrict__ rw, const float* __restrict__ iw,
    const float* __restrict__ rbv, const float* __restrict__ ibv)
{
    __shared__ short Acs[64 * SP];
    __shared__ short Ans[64 * SP];
    __shared__ short Brs[64 * SP];
    __shared__ short Bis[64 * SP];
    int tid = threadIdx.x;
    int m0 = blockIdx.x * 64, n0 = blockIdx.y * 64;
    const float* br = Br + (long long)blockIdx.z * 122880;
    const float* bi = Bi + (long long)blockIdx.z * 122880;
    float* co = Co + (long long)blockIdx.z * 196608;
    int lane = tid & 63, wid = tid >> 6;
    int wr = wid >> 1, wc = wid & 1;
    int lr = lane & 15, lg = lane >> 4;
    int nn = tid & 63, k8 = tid >> 6;
    int f = n0 + nn;
    float rd = rw[(long long)f * 384 + f];
    float id = iw[(long long)f * 384 + f];
    float rbs = rbv[f], ibs = ibv[f];
    f32x4 acc[2][2] = {};
    for (int k0 = 0; k0 < 288; k0 += 32) {
        {
            *(uint4*)(&Acs[nn * SP + k8 * 8]) =
                *(const uint4*)(Tc + (long long)(m0 + nn) * 512 + k0 + k8 * 8);
            uint4 ps = *(const uint4*)(Ts + (long long)(m0 + nn) * 512 + k0 + k8 * 8);
            ps.x ^= 0x80008000u; ps.y ^= 0x80008000u; ps.z ^= 0x80008000u; ps.w ^= 0x80008000u;
            *(uint4*)(&Ans[nn * SP + k8 * 8]) = ps;
        }
        {
            bshort8 pr, pi;
#pragma unroll
            for (int j = 0; j < 8; ++j) {
                int kg = k0 + k8 * 8 + j;
                short vr = 0, vi = 0;
                if (kg <= 256) {
                    float Re = br[(long long)kg * 384 + f];
                    float S  = bi[(long long)kg * 384 + f];
                    float wgt = (kg == 0 || kg == 256) ? 0.5f : 1.f;
                    float t1 = Re * rd + rbs, t2 = S * id;
                    float t3 = Re * id + ibs, t4 = S * rd;
                    float Rs = wgt * (fmaxf(t1 + t2, 0.f) + fmaxf(t1 - t2, 0.f));
                    float Is = wgt * (fmaxf(t3 - t4, 0.f) - fmaxf(t3 + t4, 0.f));
                    vr = f2bf(Rs);
                    vi = f2bf(Is);
                }
                pr[j] = vr;
                pi[j] = vi;
            }
            *(bshort8*)(&Brs[nn * SP + k8 * 8]) = pr;
            *(bshort8*)(&Bis[nn * SP + k8 * 8]) = pi;
        }
        __syncthreads();
        bshort8 af[2], nf[2], rf[2], iff[2];
#pragma unroll
        for (int i = 0; i < 2; ++i) {
            af[i]  = *(const bshort8*)(&Acs[(wr * 32 + i * 16 + lr) * SP + lg * 8]);
            nf[i]  = *(const bshort8*)(&Ans[(wr * 32 + i * 16 + lr) * SP + lg * 8]);
            rf[i]  = *(const bshort8*)(&Brs[(wc * 32 + i * 16 + lr) * SP + lg * 8]);
            iff[i] = *(const bshort8*)(&Bis[(wc * 32 + i * 16 + lr) * SP + lg * 8]);
        }
#pragma unroll
        for (int i = 0; i < 2; ++i)
#pragma unroll
            for (int j = 0; j < 2; ++j) {
                acc[i][j] = __builtin_amdgcn_mfma_f32_16x16x32_bf16(af[i], rf[j], acc[i][j], 0, 0, 0);
                acc[i][j] = __builtin_amdgcn_mfma_f32_16x16x32_bf16(nf[i], iff[j], acc[i][j], 0, 0, 0);
            }
        __syncthreads();
    }
#pragma unroll
    for (int i = 0; i < 2; ++i) {
        int gm = m0 + wr * 32 + i * 16 + lg * 4;
#pragma unroll
        for (int j = 0; j < 2; ++j) {
            int gn = n0 + wc * 32 + j * 16 + lr;
#pragma unroll
            for (int r = 0; r < 4; ++r)
                co[(long long)(gm + r) * 384 + gn] = acc[i][j][r];
        }
    }
}

// ---------------- causal conv(4) + silu (copy-0 rows only) ----------------
__global__ __launch_bounds__(256) void conv_silu_kernel(
    const float* __restrict__ xz, const float* __restrict__ cw,
    const float* __restrict__ cb, float* __restrict__ xc)
{
    long long idx = (long long)blockIdx.x * 256 + threadIdx.x;   // 8*512*384
    int d = (int)(idx % DIN);
    long long rt = idx / DIN;
    int t = (int)(rt & 511);
    long long base = rt - t;
    float acc = cb[d];
#pragma unroll
    for (int k = 0; k < 4; ++k) {
        int tt = t + k - 3;
        if (tt >= 0) acc = fmaf(xz[(base + tt) * 768 + d], cw[d * 4 + k], acc);
    }
    xc[idx] = acc * sigmoidf_(acc);
}

// ---------------- scan pass 1: unique 32-chunk local scans -------------------
__global__ __launch_bounds__(256) void scan_pass1(
    const float* __restrict__ xdbl0, const float* __restrict__ xc0,
    const float* __restrict__ dt_w, const float* __restrict__ dt_b,
    const float* __restrict__ A_log, float* __restrict__ ylocal,
    float* __restrict__ hpart, float* __restrict__ sumdt, float* __restrict__ cumdtg)
{
    int d0 = blockIdx.x * 32, bb = blockIdx.y, c = blockIdx.z;
    __shared__ float sBC[LCH][96];
    __shared__ unsigned sdd[LCH][32];
    __shared__ float sdtl[LCH][12];
    __shared__ float sdtw[32][12];
    __shared__ float sdtb[32];
    int tid = threadIdx.x;
    int p = tid >> 3, q = tid & 7, d = d0 + p;
    for (int i = tid; i < 384; i += 256) sdtw[i / 12][i % 12] = dt_w[(d0 + i / 12) * 12 + i % 12];
    if (tid < 32) sdtb[tid] = dt_b[d0 + tid];
    float A0 = -__expf(A_log[d * NST + 6 * q]);
    float Ad = -__expf(A_log[d * NST + 6 * q + 1]) - A0;
    long long srcbase = (long long)bb * LSEQ + c * LCH;
    for (int i = tid; i < LCH * 108; i += 256) {
        int tt = i / 108, cc = i % 108;
        float v = xdbl0[(srcbase + tt) * 108 + cc];
        if (cc < 12) sdtl[tt][cc] = v;
        else if (cc < 60) { int n = cc - 12; int qq = (n * 43) >> 8; sBC[tt][qq * 12 + (n - qq * 6)] = v; }
        else              { int n = cc - 60; int qq = (n * 43) >> 8; sBC[tt][qq * 12 + 6 + (n - qq * 6)] = v; }
    }
    __syncthreads();
    for (int i = tid; i < LCH * 32; i += 256) {
        int tt = i >> 5, j = i & 31;
        float s = sdtb[j];
#pragma unroll
        for (int r = 0; r < 12; ++r) s = fmaf(sdtl[tt][r], sdtw[j][r], s);
        s = fmaxf(s, 0.f) + log1pf(__expf(-fabsf(s)));
        float u = xc0[(srcbase + tt) * DIN + d0 + j];
        unsigned hi = (unsigned)(unsigned short)f2bf(s);
        unsigned lo = (unsigned)(unsigned short)f2bf(s * u);
        sdd[tt][j] = (hi << 16) | lo;
    }
    __syncthreads();
    float h0r = 0.f, h1r = 0.f, h2r = 0.f, h3r = 0.f, h4r = 0.f, h5r = 0.f;
    float cum = 0.f;
#pragma unroll 2
    for (int tt = 0; tt < LCH; ++tt) {
        unsigned pk = sdd[tt][p];
        float s = bfhi2f(pk), du = bflo2f(pk);
        cum += s;
        float f = __expf(s * A0);
        float w = __expf(s * Ad);
        float4 v0 = *(const float4*)&sBC[tt][q * 12];
        float4 v1 = *(const float4*)&sBC[tt][q * 12 + 4];
        float4 v2 = *(const float4*)&sBC[tt][q * 12 + 8];
        float y;
        h0r = fmaf(f, h0r, du * v0.x); y = h0r * v1.z;          f *= w;
        h1r = fmaf(f, h1r, du * v0.y); y = fmaf(h1r, v1.w, y);  f *= w;
        h2r = fmaf(f, h2r, du * v0.z); y = fmaf(h2r, v2.x, y);  f *= w;
        h3r = fmaf(f, h3r, du * v0.w); y = fmaf(h3r, v2.y, y);  f *= w;
        h4r = fmaf(f, h4r, du * v1.x); y = fmaf(h4r, v2.z, y);  f *= w;
        h5r = fmaf(f, h5r, du * v1.y); y = fmaf(h5r, v2.w, y);
        y += __shfl_xor(y, 1);
        y += __shfl_xor(y, 2);
        y += __shfl_xor(y, 4);
        if (q == 0) {
            ylocal[(srcbase + tt) * DIN + d] = y;
            cumdtg[(srcbase + tt) * DIN + d] = cum;
        }
    }
    if (q == 0) sumdt[((long long)(bb * NCH + c)) * DIN + d] = cum;
    float* hp = &hpart[(((long long)(bb * NCH + c)) * DIN + d) * NST + 6 * q];
    hp[0] = h0r; hp[1] = h1r; hp[2] = h2r; hp[3] = h3r; hp[4] = h4r; hp[5] = h5r;
}

// ---------------- scan pass 2: averaged incoming states hbar(c) --------------
__global__ __launch_bounds__(256) void scan_pass2(
    const float* __restrict__ A_log, const float* __restrict__ sumdt,
    const float* __restrict__ hpart, float* __restrict__ hbarb)
{
    long long idx = (long long)blockIdx.x * 256 + threadIdx.x;  // 8*384*48
    if (idx >= 8LL * DIN * NST) return;
    int n = (int)(idx % NST);
    long long rem = idx / NST;
    int d = (int)(rem % DIN);
    int bb = (int)(rem / DIN);
    float An = -__expf(A_log[d * NST + n]);
    float G = 0.f;
#pragma unroll
    for (int c = 0; c < NCH; ++c) {
        float nc = (float)((c >> 2) + 1);
        hbarb[(((long long)(bb * NCH + c)) * DIN + d) * NST + n] = G / nc;
        float S = hpart[(((long long)(bb * NCH + c)) * DIN + d) * NST + n];
        float P = __expf(An * sumdt[((long long)(bb * NCH + c)) * DIN + d]);
        G = fmaf(P, G, nc * S);
    }
}

// ---------------- scan pass 3: ybar = ylocal + C.(exp(A*cumdt)*hbar) ---------
#define TT3 16
__global__ __launch_bounds__(256) void scan_pass3(
    const float* __restrict__ xdbl0, const float* __restrict__ cumdtg,
    const float* __restrict__ A_log, const float* __restrict__ hbarb,
    float* __restrict__ ylocal)
{
    int c = blockIdx.z >> 1, tq = blockIdx.z & 1;
    int toff = tq * TT3;
    int d0 = blockIdx.x * 32, bb = blockIdx.y;
    __shared__ float sC[TT3][64];
    __shared__ float scum[TT3][32];
    int tid = threadIdx.x;
    int p = tid >> 3, q = tid & 7, d = d0 + p;
    float A0 = -__expf(A_log[d * NST + 6 * q]);
    float Ad = -__expf(A_log[d * NST + 6 * q + 1]) - A0;
    float g0[6];
    {
        const float* hp0 = &hbarb[(((long long)(bb * NCH + c)) * DIN + d) * NST + 6 * q];
#pragma unroll
        for (int k = 0; k < 6; ++k) g0[k] = hp0[k];
    }
    long long srcbase = (long long)bb * LSEQ + c * LCH + toff;
    for (int i = tid; i < TT3 * 48; i += 256) {
        int tt = i / 48, n = i % 48;
        int qq = (n * 43) >> 8;
        sC[tt][qq * 8 + n - qq * 6] = xdbl0[(srcbase + tt) * 108 + 60 + n];
    }
    for (int i = tid; i < TT3 * 32; i += 256) {
        int tt = i >> 5, j = i & 31;
        scum[tt][j] = cumdtg[(srcbase + tt) * DIN + d0 + j];
    }
    __syncthreads();
#pragma unroll 2
    for (int tt = 0; tt < TT3; ++tt) {
        float cd = scum[tt][p];
        float f = __expf(cd * A0);
        float w = __expf(cd * Ad);
        float4 c03 = *(const float4*)&sC[tt][q * 8];
        float4 c45 = *(const float4*)&sC[tt][q * 8 + 4];
        float a0;
        a0 = c03.x * g0[0] * f;            f *= w;
        a0 = fmaf(c03.y * g0[1], f, a0);   f *= w;
        a0 = fmaf(c03.z * g0[2], f, a0);   f *= w;
        a0 = fmaf(c03.w * g0[3], f, a0);   f *= w;
        a0 = fmaf(c45.x * g0[4], f, a0);   f *= w;
        a0 = fmaf(c45.y * g0[5], f, a0);
        a0 += __shfl_xor(a0, 1); a0 += __shfl_xor(a0, 2); a0 += __shfl_xor(a0, 4);
        if (q == 0) {
            long long yi = (srcbase + tt) * DIN + d;
            ylocal[yi] = ylocal[yi] + a0;
        }
    }
}

// ---------------- LN(norm1) + residual -> x1 + rowstats2 ---------------------
__global__ __launch_bounds__(64) void combine_ln_kernel(
    const float* __restrict__ ym, const float* __restrict__ x,
    const float* __restrict__ w, const float* __restrict__ b,
    float* __restrict__ x1, float* __restrict__ rowstats2)
{
    int row = blockIdx.x;
    int lane = threadIdx.x;
    long long base = (long long)row * CDIM;
    float vals[3];
#pragma unroll
    for (int cp = 0; cp < 3; ++cp) vals[cp] = ym[base + lane + cp * 64];
    float s1 = vals[0] + vals[1] + vals[2];
    float s2 = vals[0] * vals[0] + vals[1] * vals[1] + vals[2] * vals[2];
#pragma unroll
    for (int off = 32; off >= 1; off >>= 1) {
        s1 += __shfl_xor(s1, off);
        s2 += __shfl_xor(s2, off);
    }
    float mean = s1 * (1.f / 192.f);
    float var = s2 * (1.f / 192.f) - mean * mean;
    float rstd = rsqrtf(var + 1e-5f);
    float xv[3];
#pragma unroll
    for (int cp = 0; cp < 3; ++cp) {
        int c = lane + cp * 64;
        xv[cp] = x[base + c] + (vals[cp] - mean) * rstd * w[c] + b[c];
        x1[base + c] = xv[cp];
    }
    float t1 = xv[0] + xv[1] + xv[2];
    float t2 = xv[0] * xv[0] + xv[1] * xv[1] + xv[2] * xv[2];
#pragma unroll
    for (int off = 32; off >= 1; off >>= 1) {
        t1 += __shfl_xor(t1, off);
        t2 += __shfl_xor(t2, off);
    }
    if (lane == 0) {
        float mean2 = t1 * (1.f / 192.f);
        float var2 = t2 * (1.f / 192.f) - mean2 * mean2;
        rowstats2[row * 2] = mean2;
        rowstats2[row * 2 + 1] = rsqrtf(var2 + 1e-5f);
    }
}

// ---------------- batchnorm apply (final, with residual) ----------------
__global__ __launch_bounds__(256) void bnapply_kernel(
    const float* __restrict__ X, const float* __restrict__ stats,
    const float* __restrict__ g, const float* __restrict__ b,
    const float* __restrict__ residual, float* __restrict__ out,
    int NF, int relu, float invM)
{
    long long idx = (long long)blockIdx.x * 256 + threadIdx.x;
    int f = (int)(idx % NF);
    float mean = stats[f] * invM;
    float var = stats[NF + f] * invM - mean * mean;
    float v = (X[idx] - mean) * rsqrtf(var + 1e-5f) * g[f] + b[f];
    if (relu) v = fmaxf(v, 0.f);
    if (residual) v += residual[idx];
    out[idx] = v;
}

extern "C" void kernel_launch(void* const* d_in, const int* in_sizes, int n_in,
                              void* d_out, int out_size, void* d_ws, size_t ws_size,
                              hipStream_t stream)
{
    const float* x        = (const float*)d_in[0];
    const float* in_w     = (const float*)d_in[1];
    const float* conv_w   = (const float*)d_in[2];
    const float* conv_b   = (const float*)d_in[3];
    const float* xproj_w  = (const float*)d_in[4];
    const float* dtp_w    = (const float*)d_in[5];
    const float* dtp_b    = (const float*)d_in[6];
    const float* A_log    = (const float*)d_in[7];
    const float* D_par    = (const float*)d_in[8];
    const float* outp_w   = (const float*)d_in[9];
    const float* mnw      = (const float*)d_in[10];
    const float* mnb      = (const float*)d_in[11];
    const float* n1w      = (const float*)d_in[12];
    const float* n1b      = (const float*)d_in[13];
    const float* n2w      = (const float*)d_in[14];
    const float* n2b      = (const float*)d_in[15];
    const float* fc1_w    = (const float*)d_in[16];
    const float* bn1g     = (const float*)d_in[17];
    const float* bn1b     = (const float*)d_in[18];
    const float* r_w      = (const float*)d_in[19];
    const float* i_w      = (const float*)d_in[20];
    const float* rb       = (const float*)d_in[21];
    const float* ib       = (const float*)d_in[22];
    const float* fc2_w    = (const float*)d_in[23];
    const float* bn2g     = (const float*)d_in[24];
    const float* bn2b     = (const float*)d_in[25];
    float* out = (float*)d_out;
    float* ws = (float*)d_ws;

    // workspace (floats)
    float* x1pad  = ws;                        //  786432
    float* xz0    = x1pad  + 786432LL;         // 3145728 (z dead after out_proj)
    float* xc0    = xz0    + 3145728LL;        // 1572864 (dead after out_proj)
    float* xdbl0  = xc0    + 1572864LL;        //  442368 (dead after pass3)
    float* ylocal = xdbl0  + 442368LL;         // 1572864 (pass1->pass3->out_proj A)
    float* hbarb  = ylocal + 1572864LL;        // 2359296 (pass2->pass3)
    float* cumdtg = hbarb  + 2359296LL;        // 1572864 (pass1->pass3)
    float* hpart  = cumdtg + 1572864LL;        // 2359296 (pass1->pass2)
    float* sumdt  = hpart  + 2359296LL;        //   49152
    // dedicated (never aliased) regions:
    float* rowst1 = sumdt  + 49152LL;          //    8192 (x row stats)
    float* rowst2 = rowst1 + 8192LL;           //    8192 (x1 row stats)
    float* stats  = rowst2 + 8192LL;           //    2048 (bn1 @0, bn2 @1024)
    short* tabc_bf = (short*)(stats + 2048LL); //  262144 shorts
    short* tabs_bf = tabc_bf + 262144LL;       //  262144 shorts
    // aliases (after the producer is dead):
    float* ymout = hbarb;                      //  786432 <= 2359296 (after pass3)
    float* x1    = x1pad;
    float* hbuf  = xz0;                        // 1572864 (xz0 dead after out_proj)
    float* hfr   = xz0 + 1572864LL;            //  983040 (320x384x8)
    float* hfi   = xc0;                        //  983040 (xc0 dead after out_proj)
    float* xt    = ylocal;                     // 1572864 (ylocal dead after out_proj)
    float* g0    = hpart;                      //  786432 (hpart dead after pass2)

    // 0. prep: DFT tables + x row-stats + stats zero
    prep_kernel<<<dim3(1089), dim3(256), 0, stream>>>(tabc_bf, tabs_bf, x, rowst1, stats);

    // 2. in_proj with fused mnorm LN: xz0 = LN(x) @ in_w^T  M=4096 N=768 K=192
    gemm_mfma_kernel<64, 128, 2, 0><<<dim3(64, 6, 1), dim3(256), 0, stream>>>(
        x, in_w, xz0, 4096, 768, 192, 192, 192, 768, 0, 0, 0, 1, 0,
        nullptr, nullptr, nullptr, rowst1, mnw, mnb, nullptr, 0);

    // 3. conv + silu (separate kernel — round-17 lesson: keep it off the
    //    GEMM staging path; 6144 blocks hide the tap latency trivially)
    conv_silu_kernel<<<dim3(6144), dim3(256), 0, stream>>>(xz0, conv_w, conv_b, xc0);

    // 4. x_proj: xdbl0 = xc0 @ xproj_w^T  M=4096 N=108 K=384 (32x64: 256 blocks)
    gemm_mfma_kernel<32, 64, 0, 0><<<dim3(128, 2, 1), dim3(256), 0, stream>>>(
        xc0, xproj_w, xdbl0, 4096, 108, 384, 384, 384, 108, 0, 0, 0, 1, 0,
        nullptr, nullptr, nullptr, nullptr, nullptr, nullptr, nullptr, 0);

    // 5. selective scan
    scan_pass1<<<dim3(12, 8, NCH), dim3(256), 0, stream>>>(
        xdbl0, xc0, dtp_w, dtp_b, A_log, ylocal, hpart, sumdt, cumdtg);
    scan_pass2<<<dim3(576), dim3(256), 0, stream>>>(A_log, sumdt, hpart, hbarb);
    scan_pass3<<<dim3(12, 8, NCH * 2), dim3(256), 0, stream>>>(
        xdbl0, cumdtg, A_log, hbarb, ylocal);

    // 6+7. out_proj with fused gate on averaged y: M=4096
    gemm_mfma_kernel<32, 64, 1, 0><<<dim3(128, 3, 1), dim3(256), 0, stream>>>(
        ylocal, outp_w, ymout, 4096, 192, 384, 384, 384, 192, 0, 0, 0, 1, 0,
        xc0, xz0, D_par, nullptr, nullptr, nullptr, nullptr, 0);

    // 8+9. LN(norm1) + residual -> x1 + row stats for norm2
    combine_ln_kernel<<<dim3(NB * LSEQ), dim3(64), 0, stream>>>(
        ymout, x, n1w, n1b, x1, rowst2);

    // 10+11. fc1 with fused norm2 LN + fused bn1 column stats
    gemm_mfma_kernel<64, 64, 2, 1><<<dim3(64, 6, 1), dim3(256), 0, stream>>>(
        x1, fc1_w, hbuf, 4096, 384, 192, 192, 192, 384, 0, 0, 0, 1, 0,
        nullptr, nullptr, nullptr, rowst2, n2w, n2b, stats, 384);

    // 13. forward DFT: k=0..319 freq rows (real-input fold), bn1 fused
    dft_fwd_kernel<<<dim3(5, 6, 8), dim3(256), 0, stream>>>(
        tabc_bf, tabs_bf, hbuf, hfr, hfi, stats, bn1g, bn1b, 1.f / 4096.f);

    // 14+15. inverse DFT: K=288 (folded), freq diag+bias+relu fused
    dft_inv_kernel<<<dim3(8, 6, 8), dim3(256), 0, stream>>>(
        tabc_bf, tabs_bf, hfr, hfi, xt, r_w, i_w, rb, ib);

    // 16+17a. fc2 with fused bn2 column stats
    gemm_mfma_kernel<32, 64, 0, 1><<<dim3(128, 3, 1), dim3(256), 0, stream>>>(
        xt, fc2_w, g0, 4096, 192, 384, 384, 384, 192, 0, 0, 0, 1, 0,
        nullptr, nullptr, nullptr, nullptr, nullptr, nullptr, stats + 1024, 192);

    // 17b. bn2 apply + residual -> out
    bnapply_kernel<<<dim3(3072), dim3(256), 0, stream>>>(
        g0, stats + 1024, bn2g, bn2b, x1, out, 192, 0, 1.f / 4096.f);
}